// Round 1
// baseline (721.088 us; speedup 1.0000x reference)
//
#include <hip/hip_runtime.h>

// NEG (negative-sampling) loss:
//   loss = -(1/n) * sum_n [ log_sigmoid(<eu,ev>) + sum_k log_sigmoid(-<e_neg_k, eu>) ]
// Inputs (setup_inputs order): u[int32 N], v[int32 N], negs[int32 N*10], embs[f32 500000*256]
// Output: single f32 scalar.

#define DIM 256
#define NUM_SAMPLED 10

__device__ __forceinline__ float wave_reduce_sum(float x) {
#pragma unroll
    for (int off = 32; off > 0; off >>= 1)
        x += __shfl_xor(x, off, 64);
    return x;
}

// Numerically stable log(sigmoid(x)) = min(x,0) - log1p(exp(-|x|))
__device__ __forceinline__ float log_sigmoid(float x) {
    return fminf(x, 0.0f) - log1pf(expf(-fabsf(x)));
}

__global__ void zero_out_kernel(float* out) { *out = 0.0f; }

__global__ __launch_bounds__(256) void neg_loss_kernel(
    const int* __restrict__ u,
    const int* __restrict__ v,
    const int* __restrict__ negs,
    const float* __restrict__ embs,
    float* __restrict__ out,
    int n)
{
    const int lane = threadIdx.x & 63;
    const int wave_in_block = threadIdx.x >> 6;
    const int gwave = (blockIdx.x * blockDim.x + threadIdx.x) >> 6;
    const int waves_total = (gridDim.x * blockDim.x) >> 6;

    float acc = 0.0f;  // post-reduction values are wave-uniform; lane 0's copy is used

    for (int i = gwave; i < n; i += waves_total) {
        // wave-uniform index loads (broadcast)
        const int ui = u[i];
        const int vi = v[i];

        // lane covers elements [4*lane, 4*lane+4) of each 256-wide row:
        // 64 lanes x 16B = one fully-coalesced 1KiB burst per row.
        const float4 eu = *reinterpret_cast<const float4*>(embs + (size_t)ui * DIM + lane * 4);
        const float4 ev = *reinterpret_cast<const float4*>(embs + (size_t)vi * DIM + lane * 4);

        float pos = eu.x * ev.x + eu.y * ev.y + eu.z * ev.z + eu.w * ev.w;

        float s[NUM_SAMPLED];
#pragma unroll
        for (int k = 0; k < NUM_SAMPLED; ++k) {
            const int nk = negs[i * NUM_SAMPLED + k];
            const float4 en = *reinterpret_cast<const float4*>(embs + (size_t)nk * DIM + lane * 4);
            // scores = <-e_neg, eu>
            s[k] = -(eu.x * en.x + eu.y * en.y + eu.z * en.z + eu.w * en.w);
        }

        float loss = log_sigmoid(wave_reduce_sum(pos));
#pragma unroll
        for (int k = 0; k < NUM_SAMPLED; ++k) {
            loss += log_sigmoid(wave_reduce_sum(s[k]));
        }
        acc += loss;
    }

    // block reduction: one partial per wave -> thread 0 -> one atomic per block
    __shared__ float wave_acc[4];
    if (lane == 0) wave_acc[wave_in_block] = acc;
    __syncthreads();
    if (threadIdx.x == 0) {
        float b = wave_acc[0] + wave_acc[1] + wave_acc[2] + wave_acc[3];
        atomicAdd(out, b * (-1.0f / n));
    }
}

extern "C" void kernel_launch(void* const* d_in, const int* in_sizes, int n_in,
                              void* d_out, int out_size, void* d_ws, size_t ws_size,
                              hipStream_t stream) {
    const int*   u    = (const int*)d_in[0];
    const int*   v    = (const int*)d_in[1];
    const int*   negs = (const int*)d_in[2];
    const float* embs = (const float*)d_in[3];
    float* out = (float*)d_out;

    const int n = in_sizes[0];  // 65536

    // d_out is poisoned to 0xAA before every timed launch -> must zero it here.
    zero_out_kernel<<<1, 1, 0, stream>>>(out);

    // one sample per wave; 2048 blocks x 4 waves = 8192 waves, grid-stride (8 samples/wave)
    const int blocks = 2048;
    neg_loss_kernel<<<blocks, 256, 0, stream>>>(u, v, negs, embs, out, n);
}

// Round 2
// 673.027 us; speedup vs baseline: 1.0714x; 1.0714x over previous
//
#include <hip/hip_runtime.h>

// NEG (negative-sampling) loss:
//   loss = -(1/n) * sum_n [ log_sigmoid(<eu,ev>) + sum_k log_sigmoid(-<e_neg_k, eu>) ]
// Inputs (setup_inputs order): u[int32 N], v[int32 N], negs[int32 N*10], embs[f32 500000*256]
// Output: single f32 scalar.
//
// Layout: one sample per 16-lane group (4 samples/wave, 16/block).
//   - lane j<10 loads negs[i*10+j], j==10 loads u[i], j==11 loads v[i]; __shfl distributes.
//   - row chunk c (c=0..3): lane j16 loads float4 at row*256 + c*64 + j16*4
//     -> each wave-wide load = 4 contiguous 256B segments (ideal coalescing).
//   - 4-stage xor-butterfly (offsets 1,2,4,8) allreduces 11 dots within the group.

#define DIM 256
#define NUM_SAMPLED 10

__device__ __forceinline__ float log_sigmoid(float x) {
    // stable: min(x,0) - log1p(exp(-|x|))
    return fminf(x, 0.0f) - log1pf(expf(-fabsf(x)));
}

__global__ void zero_out_kernel(float* out) { *out = 0.0f; }

__global__ __launch_bounds__(256) void neg_loss_kernel(
    const int* __restrict__ u,
    const int* __restrict__ v,
    const int* __restrict__ negs,
    const float* __restrict__ embs,
    float* __restrict__ out,
    int n)
{
    const int lane16 = threadIdx.x & 15;          // lane within 16-lane group
    const int group  = threadIdx.x >> 4;          // group in block: 0..15
    const int i      = blockIdx.x * 16 + group;   // sample id
    const int wbase  = threadIdx.x & 48;          // group base within the wave (0,16,32,48)

    // ---- lane-parallel index load (12 useful lanes per group) ----
    int idx = 0;
    if (i < n) {
        if (lane16 < NUM_SAMPLED)        idx = negs[(size_t)i * NUM_SAMPLED + lane16];
        else if (lane16 == NUM_SAMPLED)  idx = u[i];
        else if (lane16 == 11)           idx = v[i];
    }

    const int iu = __shfl(idx, wbase + 10, 64);
    const int iv = __shfl(idx, wbase + 11, 64);
    int ik[NUM_SAMPLED];
#pragma unroll
    for (int k = 0; k < NUM_SAMPLED; ++k) ik[k] = __shfl(idx, wbase + k, 64);

    // ---- gather rows; each lane covers 16 floats of the 256-dim row ----
    const float* pu = embs + (size_t)iu * DIM + lane16 * 4;
    const float* pv = embs + (size_t)iv * DIM + lane16 * 4;

    float4 eu[4];
#pragma unroll
    for (int c = 0; c < 4; ++c) eu[c] = *reinterpret_cast<const float4*>(pu + c * 64);

    float s[NUM_SAMPLED + 1];

    {
        float p = 0.0f;
#pragma unroll
        for (int c = 0; c < 4; ++c) {
            const float4 ev = *reinterpret_cast<const float4*>(pv + c * 64);
            p += eu[c].x * ev.x + eu[c].y * ev.y + eu[c].z * ev.z + eu[c].w * ev.w;
        }
        s[0] = p;
    }

#pragma unroll
    for (int k = 0; k < NUM_SAMPLED; ++k) {
        const float* pn = embs + (size_t)ik[k] * DIM + lane16 * 4;
        float d = 0.0f;
#pragma unroll
        for (int c = 0; c < 4; ++c) {
            const float4 en = *reinterpret_cast<const float4*>(pn + c * 64);
            d += eu[c].x * en.x + eu[c].y * en.y + eu[c].z * en.z + eu[c].w * en.w;
        }
        s[k + 1] = -d;   // score = <-e_neg, eu>
    }

    // ---- 4-stage butterfly allreduce within the 16-lane group ----
#pragma unroll
    for (int off = 1; off < 16; off <<= 1) {
#pragma unroll
        for (int j = 0; j < NUM_SAMPLED + 1; ++j)
            s[j] += __shfl_xor(s[j], off, 64);
    }

    float loss = 0.0f;
#pragma unroll
    for (int j = 0; j < NUM_SAMPLED + 1; ++j) loss += log_sigmoid(s[j]);

    // ---- block reduce: one value per group -> one atomic per block ----
    __shared__ float g_acc[16];
    if (lane16 == 0) g_acc[group] = (i < n) ? loss : 0.0f;
    __syncthreads();
    if (threadIdx.x == 0) {
        float b = 0.0f;
#pragma unroll
        for (int g = 0; g < 16; ++g) b += g_acc[g];
        atomicAdd(out, b * (-1.0f / n));
    }
}

extern "C" void kernel_launch(void* const* d_in, const int* in_sizes, int n_in,
                              void* d_out, int out_size, void* d_ws, size_t ws_size,
                              hipStream_t stream) {
    const int*   u    = (const int*)d_in[0];
    const int*   v    = (const int*)d_in[1];
    const int*   negs = (const int*)d_in[2];
    const float* embs = (const float*)d_in[3];
    float* out = (float*)d_out;

    const int n = in_sizes[0];  // 65536

    // d_out is poisoned to 0xAA before every timed launch -> zero it first.
    zero_out_kernel<<<1, 1, 0, stream>>>(out);

    const int blocks = (n + 15) / 16;  // 16 samples per block (4 per wave)
    neg_loss_kernel<<<blocks, 256, 0, stream>>>(u, v, negs, embs, out, n);
}